// Round 1
// baseline (50341.580 us; speedup 1.0000x reference)
//
#include <hip/hip_runtime.h>
#include <cmath>

// Problem constants (fixed by the reference).
#define B_SZ 512
#define T_SZ 256
#define I_SZ 256
#define H_SZ 1024
#define V_SZ 1024
#define E_SZ 8
#define FUT 64

#define BM 64
#define BN 64
#define KC 16

// ---------------------------------------------------------------------------
// Fused two-operand GEMM:
//   Z[m, n] = bias[n] + sum_k A1[m, k] * W1[n, k]   (k < K1)
//                     + sum_k A2[m, k] * W2[n, k]   (k < K2, optional)
// A row stride = lda; W is [N, K] row-major (K contiguous) — both operands
// dot along contiguous K (weights stored transposed, PyTorch-style).
// Grid: (N/BN, M/BM), block 256 threads, 4x4 microtile per thread.
// ---------------------------------------------------------------------------
__global__ __launch_bounds__(256) void gemm2_kernel(
    const float* __restrict__ A1, int lda1, const float* __restrict__ W1, int K1,
    const float* __restrict__ A2, int lda2, const float* __restrict__ W2, int K2,
    const float* __restrict__ bias, float* __restrict__ Z, int ldz)
{
    __shared__ float as[KC][BM + 1];
    __shared__ float ws[KC][BN + 1];

    const int tid = threadIdx.x;
    const int tx = tid & 15;   // -> n microtile
    const int ty = tid >> 4;   // -> m microtile
    const int m0 = blockIdx.y * BM;
    const int n0 = blockIdx.x * BN;
    const int lk = tid & 15;   // loader: k within chunk
    const int lr = tid >> 4;   // loader: base row

    float acc[4][4];
#pragma unroll
    for (int i = 0; i < 4; ++i)
#pragma unroll
        for (int j = 0; j < 4; ++j) acc[i][j] = 0.f;

    // ---- pass 1: A1 / W1 over K1 ----
    for (int k0 = 0; k0 < K1; k0 += KC) {
#pragma unroll
        for (int r = 0; r < 4; ++r) {
            const int row = lr + r * 16;
            const int k = k0 + lk;
            float av = 0.f, wv = 0.f;
            if (k < K1) {
                av = A1[(size_t)(m0 + row) * lda1 + k];
                wv = W1[(size_t)(n0 + row) * K1 + k];
            }
            as[lk][row] = av;
            ws[lk][row] = wv;
        }
        __syncthreads();
#pragma unroll
        for (int k = 0; k < KC; ++k) {
            float a[4], w[4];
#pragma unroll
            for (int i = 0; i < 4; ++i) a[i] = as[k][ty * 4 + i];
#pragma unroll
            for (int j = 0; j < 4; ++j) w[j] = ws[k][tx * 4 + j];
#pragma unroll
            for (int i = 0; i < 4; ++i)
#pragma unroll
                for (int j = 0; j < 4; ++j)
                    acc[i][j] = fmaf(a[i], w[j], acc[i][j]);
        }
        __syncthreads();
    }

    // ---- pass 2: A2 / W2 over K2 (K2 may be 0) ----
    for (int k0 = 0; k0 < K2; k0 += KC) {
#pragma unroll
        for (int r = 0; r < 4; ++r) {
            const int row = lr + r * 16;
            const int k = k0 + lk;
            float av = 0.f, wv = 0.f;
            if (k < K2) {
                av = A2[(size_t)(m0 + row) * lda2 + k];
                wv = W2[(size_t)(n0 + row) * K2 + k];
            }
            as[lk][row] = av;
            ws[lk][row] = wv;
        }
        __syncthreads();
#pragma unroll
        for (int k = 0; k < KC; ++k) {
            float a[4], w[4];
#pragma unroll
            for (int i = 0; i < 4; ++i) a[i] = as[k][ty * 4 + i];
#pragma unroll
            for (int j = 0; j < 4; ++j) w[j] = ws[k][tx * 4 + j];
#pragma unroll
            for (int i = 0; i < 4; ++i)
#pragma unroll
                for (int j = 0; j < 4; ++j)
                    acc[i][j] = fmaf(a[i], w[j], acc[i][j]);
        }
        __syncthreads();
    }

    // ---- epilogue ----
#pragma unroll
    for (int i = 0; i < 4; ++i) {
        const int m = m0 + ty * 4 + i;
#pragma unroll
        for (int j = 0; j < 4; ++j) {
            const int n = n0 + tx * 4 + j;
            Z[(size_t)m * ldz + n] = acc[i][j] + bias[n];
        }
    }
}

// ---------------------------------------------------------------------------
// LSTM pointwise gates: z is [B, 4H] with PyTorch gate order i,f,g,o.
// ---------------------------------------------------------------------------
__global__ __launch_bounds__(256) void lstm_gates(
    const float* __restrict__ z, float* __restrict__ h, float* __restrict__ c)
{
    const int idx = blockIdx.x * 256 + threadIdx.x;  // < B*H
    const int b = idx >> 10;
    const int j = idx & (H_SZ - 1);
    const float* zr = z + (size_t)b * (4 * H_SZ);
    const float zi = zr[j];
    const float zf = zr[j + H_SZ];
    const float zg = zr[j + 2 * H_SZ];
    const float zo = zr[j + 3 * H_SZ];
    const float ig = 1.f / (1.f + expf(-zi));
    const float fg = 1.f / (1.f + expf(-zf));
    const float gg = tanhf(zg);
    const float og = 1.f / (1.f + expf(-zo));
    const float cn = fg * c[idx] + ig * gg;
    c[idx] = cn;
    h[idx] = og * tanhf(cn);
}

// ---------------------------------------------------------------------------
// Row-wise argmax with first-occurrence tie-breaking (matches jnp.argmax).
// One block of 256 threads per row; V = 1024.
// ---------------------------------------------------------------------------
__global__ __launch_bounds__(256) void argmax_rows(
    const float* __restrict__ logits, int row_stride, int* __restrict__ y)
{
    const int b = blockIdx.x;
    const float* row = logits + (size_t)b * row_stride;
    const int tid = threadIdx.x;
    float best = -INFINITY;
    int bidx = 0x7fffffff;
    for (int v = tid; v < V_SZ; v += 256) {
        const float x = row[v];
        if (x > best) { best = x; bidx = v; }  // strict > keeps earliest v
    }
    __shared__ float sv[256];
    __shared__ int si[256];
    sv[tid] = best;
    si[tid] = bidx;
    __syncthreads();
    for (int s = 128; s > 0; s >>= 1) {
        if (tid < s) {
            const float ov = sv[tid + s];
            const int oi = si[tid + s];
            if (ov > sv[tid] || (ov == sv[tid] && oi < si[tid])) {
                sv[tid] = ov;
                si[tid] = oi;
            }
        }
        __syncthreads();
    }
    if (tid == 0) y[b] = si[0];
}

// ---------------------------------------------------------------------------
// Embedding gather: x[b, :] = embed_W[y[b], :], E = 8.
// ---------------------------------------------------------------------------
__global__ void embed_gather(
    const float* __restrict__ embed_W, const int* __restrict__ y,
    float* __restrict__ x)
{
    const int idx = blockIdx.x * 256 + threadIdx.x;  // < B*E = 4096
    const int b = idx >> 3;
    const int e = idx & 7;
    x[idx] = embed_W[(size_t)y[b] * E_SZ + e];
}

// ---------------------------------------------------------------------------
// Zero h, c, y (workspace is poisoned with 0xAA by the harness).
// ---------------------------------------------------------------------------
__global__ void init_state(float* __restrict__ h, float* __restrict__ c,
                           int* __restrict__ y)
{
    const int idx = blockIdx.x * 256 + threadIdx.x;  // covers B*H
    h[idx] = 0.f;
    c[idx] = 0.f;
    if (idx < B_SZ) y[idx] = 0;
}

extern "C" void kernel_launch(void* const* d_in, const int* in_sizes, int n_in,
                              void* d_out, int out_size, void* d_ws, size_t ws_size,
                              hipStream_t stream)
{
    const float* x_hist  = (const float*)d_in[0];
    const float* enc_Wih = (const float*)d_in[1];
    const float* enc_Whh = (const float*)d_in[2];
    const float* enc_b   = (const float*)d_in[3];
    const float* embed_W = (const float*)d_in[4];
    const float* dec_Wih = (const float*)d_in[5];
    const float* dec_Whh = (const float*)d_in[6];
    const float* dec_b   = (const float*)d_in[7];
    const float* fc_W    = (const float*)d_in[8];
    const float* fc_b    = (const float*)d_in[9];
    float* out = (float*)d_out;

    // Workspace layout (all offsets 256B-aligned):
    //   h  : [512, 1024] f32   @ 0        (2 MB)
    //   c  : [512, 1024] f32   @ 2 MB     (2 MB)
    //   z  : [512, 4096] f32   @ 4 MB     (8 MB)
    //   xd : [512, 8]    f32   @ 12 MB    (16 KB)
    //   y  : [512]       i32   @ 12 MB + 16 KB (2 KB)
    char* ws = (char*)d_ws;
    float* h  = (float*)(ws);
    float* c  = (float*)(ws + (2ull << 20));
    float* z  = (float*)(ws + (4ull << 20));
    float* xd = (float*)(ws + (12ull << 20));
    int*   y  = (int*)(ws + (12ull << 20) + 16384);

    const dim3 blk(256);
    const dim3 gridInit((B_SZ * H_SZ) / 256);       // 2048
    const dim3 gridGates((B_SZ * H_SZ) / 256);      // 2048
    const dim3 gridZ((4 * H_SZ) / BN, B_SZ / BM);   // (64, 8)
    const dim3 gridFC(V_SZ / BN, B_SZ / BM);        // (16, 8)
    const dim3 gridEmb((B_SZ * E_SZ) / 256);        // 16
    const dim3 gridAmax(B_SZ);                      // 512

    hipLaunchKernelGGL(init_state, gridInit, blk, 0, stream, h, c, y);

    // ---- Encoder: 256 sequential LSTM steps ----
    for (int t = 0; t < T_SZ; ++t) {
        hipLaunchKernelGGL(gemm2_kernel, gridZ, blk, 0, stream,
                           x_hist + (size_t)t * I_SZ, T_SZ * I_SZ, enc_Wih, I_SZ,
                           h, H_SZ, enc_Whh, H_SZ,
                           enc_b, z, 4 * H_SZ);
        hipLaunchKernelGGL(lstm_gates, gridGates, blk, 0, stream, z, h, c);
    }

    // ---- Decoder: 64 autoregressive steps ----
    for (int t = 0; t < FUT; ++t) {
        hipLaunchKernelGGL(embed_gather, gridEmb, blk, 0, stream, embed_W, y, xd);
        hipLaunchKernelGGL(gemm2_kernel, gridZ, blk, 0, stream,
                           xd, E_SZ, dec_Wih, E_SZ,
                           h, H_SZ, dec_Whh, H_SZ,
                           dec_b, z, 4 * H_SZ);
        hipLaunchKernelGGL(lstm_gates, gridGates, blk, 0, stream, z, h, c);
        float* logits = out + (size_t)t * V_SZ;  // [B, FUT, V]: row b at b*FUT*V
        hipLaunchKernelGGL(gemm2_kernel, gridFC, blk, 0, stream,
                           h, H_SZ, fc_W, H_SZ,
                           (const float*)nullptr, 0, (const float*)nullptr, 0,
                           fc_b, logits, FUT * V_SZ);
        hipLaunchKernelGGL(argmax_rows, gridAmax, blk, 0, stream,
                           logits, FUT * V_SZ, y);
    }
}

// Round 2
// 22332.387 us; speedup vs baseline: 2.2542x; 2.2542x over previous
//
#include <hip/hip_runtime.h>
#include <cmath>

typedef __attribute__((ext_vector_type(8))) short short8;
typedef __attribute__((ext_vector_type(4))) float f32x4;

#define B_SZ 512
#define T_SZ 256
#define I_SZ 256
#define H_SZ 1024
#define V_SZ 1024
#define E_SZ 8
#define FUT 64

// Split-bf16 concatenated K layouts:
//   enc A: [x_hi(256) | x_hi(256) | x_lo(256) | h_hi(1024) | h_hi(1024) | h_lo(1024)]
//   dec A: [xc(64: x_hi8|x_hi8|x_lo8|0*40)   | h_hi(1024) | h_hi(1024) | h_lo(1024)]
//   fc  A: hcat = [h_hi | h_hi | h_lo]  (lives inside dec A at col 64)
#define KENC 3840
#define KDEC 3136
#define KFC  3072

static __device__ __forceinline__ ushort f2bf(float v) {
    uint32_t u = __float_as_uint(v);
    uint32_t r = (u + 0x7fffu + ((u >> 16) & 1u)) >> 16;
    return (ushort)r;
}
static __device__ __forceinline__ float bf2f(ushort b) {
    return __uint_as_float(((uint32_t)b) << 16);
}

#define GLD16(gp, lp)                                                          \
    __builtin_amdgcn_global_load_lds(                                         \
        (const __attribute__((address_space(1))) void*)(gp),                  \
        (__attribute__((address_space(3))) void*)(lp), 16, 0, 0)

// ---------------------------------------------------------------------------
// Fused LSTM step: Z[512,4096] = A[512,K] @ W[4096,K]^T (bf16 MFMA, fp32 acc)
// with gate-permuted columns (n' = jhi*64 + g*16 + jlo), then gates + c update
// + h split written as bf16 hi/lo into the NEXT step's A buffer. Optionally
// converts x_{t+1} into the next A buffer too.
// Tile 64(M) x 128(N'), BK=64, 4 waves (2x2), wave tile 32x64. Grid: 256 flat.
// ---------------------------------------------------------------------------
__global__ __launch_bounds__(256) void lstm_step(
    const ushort* __restrict__ A, int K,
    const ushort* __restrict__ W,
    const float* __restrict__ bias,          // [4096] gate-permuted
    float* __restrict__ c,                   // [512,1024] fp32, in-place
    ushort* __restrict__ hdest, int ldh,     // hcat base: writes j, 1024+j, 2048+j
    const float* __restrict__ xsrc,          // x_hist + (t+1)*I (row stride T*I) or null
    ushort* __restrict__ xdest)              // next A_enc base or null
{
    __shared__ __align__(16) ushort As[2][64 * 64];
    __shared__ __align__(16) ushort Ws[2][128 * 64];

    const int tid = threadIdx.x;
    const int lane = tid & 63;
    const int wid = tid >> 6;
    const int wm = wid >> 1;            // 0..1
    const int wn = wid & 1;             // 0..1

    // XCD swizzle: xcd = flat&7 owns a contiguous 512-col slice of W (L2-fit).
    const int flat = blockIdx.x;        // 0..255
    const int slot = flat >> 3;
    const int n_blk = (flat & 7) * 4 + (slot & 3);   // 0..31
    const int m_blk = slot >> 2;                     // 0..7
    const int m0 = m_blk * 64;
    const int n0 = n_blk * 128;

    const int lrow = lane >> 3;          // 0..7
    const int lcol = (lane & 7) * 8;     // bf16 elems

    f32x4 acc[2][4];
#pragma unroll
    for (int i = 0; i < 2; ++i)
#pragma unroll
        for (int j = 0; j < 4; ++j) { f32x4 z = {0.f, 0.f, 0.f, 0.f}; acc[i][j] = z; }

    const int nk = K / 64;

    // prologue: stage chunk 0 into buf 0
#pragma unroll
    for (int r = 0; r < 2; ++r)
        GLD16(A + (size_t)(m0 + r * 32 + wid * 8 + lrow) * K + lcol,
              &As[0][(r * 32 + wid * 8) * 64]);
#pragma unroll
    for (int r = 0; r < 4; ++r)
        GLD16(W + (size_t)(n0 + r * 32 + wid * 8 + lrow) * K + lcol,
              &Ws[0][(r * 32 + wid * 8) * 64]);

    int buf = 0;
    for (int kt = 0; kt < nk; ++kt) {
        __syncthreads();                 // drains vmcnt: chunk `buf` is ready
        if (kt + 1 < nk) {
            const int k0 = (kt + 1) * 64;
#pragma unroll
            for (int r = 0; r < 2; ++r)
                GLD16(A + (size_t)(m0 + r * 32 + wid * 8 + lrow) * K + k0 + lcol,
                      &As[buf ^ 1][(r * 32 + wid * 8) * 64]);
#pragma unroll
            for (int r = 0; r < 4; ++r)
                GLD16(W + (size_t)(n0 + r * 32 + wid * 8 + lrow) * K + k0 + lcol,
                      &Ws[buf ^ 1][(r * 32 + wid * 8) * 64]);
        }
#pragma unroll
        for (int kk = 0; kk < 2; ++kk) {
            short8 af[2], wf[4];
#pragma unroll
            for (int m = 0; m < 2; ++m)
                af[m] = *(const short8*)&As[buf][(wm * 32 + m * 16 + (lane & 15)) * 64 +
                                                 kk * 32 + (lane >> 4) * 8];
#pragma unroll
            for (int n = 0; n < 4; ++n)
                wf[n] = *(const short8*)&Ws[buf][(wn * 64 + n * 16 + (lane & 15)) * 64 +
                                                 kk * 32 + (lane >> 4) * 8];
#pragma unroll
            for (int m = 0; m < 2; ++m)
#pragma unroll
                for (int n = 0; n < 4; ++n)
                    acc[m][n] = __builtin_amdgcn_mfma_f32_16x16x32_bf16(
                        af[m], wf[n], acc[m][n], 0, 0, 0);
        }
        buf ^= 1;
    }

    // ---- fused gate epilogue ----
    const int jlo = lane & 15;
    const int rg = lane >> 4;
    const int nb = n0 + wn * 64;                 // 64-aligned
    const int j = (nb >> 6) * 16 + jlo;          // h column
    const float bi_ = bias[nb + jlo];
    const float bf_ = bias[nb + 16 + jlo];
    const float bg_ = bias[nb + 32 + jlo];
    const float bo_ = bias[nb + 48 + jlo];
#pragma unroll
    for (int m = 0; m < 2; ++m) {
        const int row0 = m0 + wm * 32 + m * 16 + rg * 4;
#pragma unroll
        for (int r = 0; r < 4; ++r) {
            const int row = row0 + r;
            const float zi = acc[m][0][r] + bi_;
            const float zf = acc[m][1][r] + bf_;
            const float zg = acc[m][2][r] + bg_;
            const float zo = acc[m][3][r] + bo_;
            const float ig = 1.f / (1.f + expf(-zi));
            const float fg = 1.f / (1.f + expf(-zf));
            const float gg = tanhf(zg);
            const float og = 1.f / (1.f + expf(-zo));
            const size_t ci = (size_t)row * H_SZ + j;
            const float cn = fg * c[ci] + ig * gg;
            c[ci] = cn;
            const float hv = og * tanhf(cn);
            const ushort hh = f2bf(hv);
            const ushort hl = f2bf(hv - bf2f(hh));
            ushort* hd = hdest + (size_t)row * ldh;
            hd[j] = hh;
            hd[H_SZ + j] = hh;
            hd[2 * H_SZ + j] = hl;
        }
    }

    // ---- fused x_{t+1} hi/lo conversion into next A buffer ----
    if (xdest) {
        const int ft = (blockIdx.x * 256 + tid) * 2;   // 131072 elems total
#pragma unroll
        for (int e = 0; e < 2; ++e) {
            const int idx = ft + e;
            const int b = idx >> 8, i = idx & 255;
            const float v = xsrc[(size_t)b * (T_SZ * I_SZ) + i];
            const ushort hi = f2bf(v), lo = f2bf(v - bf2f(hi));
            ushort* xd = xdest + (size_t)b * KENC;
            xd[i] = hi;
            xd[256 + i] = hi;
            xd[512 + i] = lo;
        }
    }
}

// ---------------------------------------------------------------------------
// fc GEMM: logits[512,1024] = hcat[512,3072] @ W_fc[1024,3072]^T + fc_b.
// Tile 32x64, 4 waves (2x2), wave tile 16x32. Grid: 256 flat (XCD-swizzled).
// ---------------------------------------------------------------------------
__global__ __launch_bounds__(256) void fc_gemm(
    const ushort* __restrict__ A, int lda,
    const ushort* __restrict__ W,
    const float* __restrict__ bias,
    float* __restrict__ out, int ldo)
{
    __shared__ __align__(16) ushort As[2][32 * 64];
    __shared__ __align__(16) ushort Ws[2][64 * 64];
    const int tid = threadIdx.x, lane = tid & 63, wid = tid >> 6;
    const int wm = wid >> 1, wn = wid & 1;
    const int flat = blockIdx.x;
    const int slot = flat >> 3;
    const int n_blk = (flat & 7) * 2 + (slot & 1);   // 0..15
    const int m_blk = slot >> 1;                     // 0..15
    const int m0 = m_blk * 32, n0 = n_blk * 64;
    const int lrow = lane >> 3, lcol = (lane & 7) * 8;

    f32x4 acc[2];
    { f32x4 z = {0.f, 0.f, 0.f, 0.f}; acc[0] = z; acc[1] = z; }
    const int nk = KFC / 64;   // 48

    GLD16(A + (size_t)(m0 + wid * 8 + lrow) * lda + lcol, &As[0][(wid * 8) * 64]);
#pragma unroll
    for (int r = 0; r < 2; ++r)
        GLD16(W + (size_t)(n0 + r * 32 + wid * 8 + lrow) * KFC + lcol,
              &Ws[0][(r * 32 + wid * 8) * 64]);

    int buf = 0;
    for (int kt = 0; kt < nk; ++kt) {
        __syncthreads();
        if (kt + 1 < nk) {
            const int k0 = (kt + 1) * 64;
            GLD16(A + (size_t)(m0 + wid * 8 + lrow) * lda + k0 + lcol,
                  &As[buf ^ 1][(wid * 8) * 64]);
#pragma unroll
            for (int r = 0; r < 2; ++r)
                GLD16(W + (size_t)(n0 + r * 32 + wid * 8 + lrow) * KFC + k0 + lcol,
                      &Ws[buf ^ 1][(r * 32 + wid * 8) * 64]);
        }
#pragma unroll
        for (int kk = 0; kk < 2; ++kk) {
            const short8 af = *(const short8*)&As[buf][(wm * 16 + (lane & 15)) * 64 +
                                                       kk * 32 + (lane >> 4) * 8];
            short8 wf[2];
#pragma unroll
            for (int n = 0; n < 2; ++n)
                wf[n] = *(const short8*)&Ws[buf][(wn * 32 + n * 16 + (lane & 15)) * 64 +
                                                 kk * 32 + (lane >> 4) * 8];
#pragma unroll
            for (int n = 0; n < 2; ++n)
                acc[n] = __builtin_amdgcn_mfma_f32_16x16x32_bf16(af, wf[n], acc[n], 0, 0, 0);
        }
        buf ^= 1;
    }

    const int jl = lane & 15, rg = lane >> 4;
#pragma unroll
    for (int n = 0; n < 2; ++n) {
        const int col = n0 + wn * 32 + n * 16 + jl;
        const float bv = bias[col];
#pragma unroll
        for (int r = 0; r < 4; ++r) {
            const int row = m0 + wm * 16 + rg * 4 + r;
            out[(size_t)row * ldo + col] = acc[n][r] + bv;
        }
    }
}

// ---------------------------------------------------------------------------
// Row argmax (first-occurrence) fused with embedding gather + hi/lo split
// into the next decoder A buffer's xcomb columns.
// ---------------------------------------------------------------------------
__global__ __launch_bounds__(256) void argmax_embed(
    const float* __restrict__ logits, int ldl,
    const float* __restrict__ embed_W,
    ushort* __restrict__ xdest)
{
    const int b = blockIdx.x;
    const float* row = logits + (size_t)b * ldl;
    const int tid = threadIdx.x;
    float best = -INFINITY;
    int bi = V_SZ;
#pragma unroll
    for (int v = tid; v < V_SZ; v += 256) {
        const float x = row[v];
        if (x > best) { best = x; bi = v; }
    }
    __shared__ float sv[256];
    __shared__ int si[256];
    sv[tid] = best; si[tid] = bi;
    __syncthreads();
    for (int s = 128; s > 0; s >>= 1) {
        if (tid < s) {
            const float ov = sv[tid + s]; const int oi = si[tid + s];
            if (ov > sv[tid] || (ov == sv[tid] && oi < si[tid])) { sv[tid] = ov; si[tid] = oi; }
        }
        __syncthreads();
    }
    if (tid < E_SZ) {
        const int yb = si[0];
        const float v = embed_W[(size_t)yb * E_SZ + tid];
        const ushort hi = f2bf(v), lo = f2bf(v - bf2f(hi));
        ushort* xd = xdest + (size_t)b * KDEC;
        xd[tid] = hi;
        xd[8 + tid] = hi;
        xd[16 + tid] = lo;
    }
}

// ---------------------------------------------------------------------------
// Weight packing (gate-permuted rows, split-bf16 concatenated K).
// ---------------------------------------------------------------------------
__global__ void pack_enc(const float* __restrict__ Wih, const float* __restrict__ Whh,
                         const float* __restrict__ b, ushort* __restrict__ Wp,
                         float* __restrict__ bp)
{
    const int k = blockIdx.x * 256 + threadIdx.x;   // < 3840
    const int np = blockIdx.y;                      // < 4096
    const int orig = ((np >> 4) & 3) * H_SZ + (np >> 6) * 16 + (np & 15);
    float v; bool lo = false;
    if (k < 256)        v = Wih[(size_t)orig * I_SZ + k];
    else if (k < 512) { v = Wih[(size_t)orig * I_SZ + k - 256]; lo = true; }
    else if (k < 768)   v = Wih[(size_t)orig * I_SZ + k - 512];
    else if (k < 1792)  v = Whh[(size_t)orig * H_SZ + k - 768];
    else if (k < 2816) { v = Whh[(size_t)orig * H_SZ + k - 1792]; lo = true; }
    else                v = Whh[(size_t)orig * H_SZ + k - 2816];
    const ushort hi = f2bf(v);
    Wp[(size_t)np * KENC + k] = lo ? f2bf(v - bf2f(hi)) : hi;
    if (k == 0) bp[np] = b[orig];
}

__global__ void pack_dec(const float* __restrict__ Wih, const float* __restrict__ Whh,
                         const float* __restrict__ b, ushort* __restrict__ Wp,
                         float* __restrict__ bp)
{
    const int k = blockIdx.x * 256 + threadIdx.x;
    const int np = blockIdx.y;
    if (k >= KDEC) return;
    const int orig = ((np >> 4) & 3) * H_SZ + (np >> 6) * 16 + (np & 15);
    float v = 0.f; bool lo = false;
    if (k < 8)          v = Wih[(size_t)orig * E_SZ + k];
    else if (k < 16)  { v = Wih[(size_t)orig * E_SZ + k - 8]; lo = true; }
    else if (k < 24)    v = Wih[(size_t)orig * E_SZ + k - 16];
    else if (k < 64)    v = 0.f;
    else if (k < 1088)  v = Whh[(size_t)orig * H_SZ + k - 64];
    else if (k < 2112) { v = Whh[(size_t)orig * H_SZ + k - 1088]; lo = true; }
    else                v = Whh[(size_t)orig * H_SZ + k - 2112];
    const ushort hi = f2bf(v);
    Wp[(size_t)np * KDEC + k] = lo ? f2bf(v - bf2f(hi)) : hi;
    if (k == 0) bp[np] = b[orig];
}

__global__ void pack_fc(const float* __restrict__ W, ushort* __restrict__ Wp)
{
    const int k = blockIdx.x * 256 + threadIdx.x;   // < 3072
    const int np = blockIdx.y;                      // < 1024
    float v; bool lo = false;
    if (k < 1024)       v = W[(size_t)np * H_SZ + k];
    else if (k < 2048) { v = W[(size_t)np * H_SZ + k - 1024]; lo = true; }
    else                v = W[(size_t)np * H_SZ + k - 2048];
    const ushort hi = f2bf(v);
    Wp[(size_t)np * KFC + k] = lo ? f2bf(v - bf2f(hi)) : hi;
}

// ---------------------------------------------------------------------------
// Init: zero c, zero h-region of A_enc[0], convert x(0), write xcomb(0) from
// embed row 0, zero the pad columns of both decoder A buffers.
// ---------------------------------------------------------------------------
__global__ void init_all(const float* __restrict__ x0,
                         const float* __restrict__ embed_W,
                         float* __restrict__ c,
                         ushort* __restrict__ Aenc0,
                         ushort* __restrict__ Adec0,
                         ushort* __restrict__ Adec1)
{
    const int idx = blockIdx.x * 256 + threadIdx.x;   // < 512*3072
    {
        const int b = idx / 3072, k = idx % 3072;
        Aenc0[(size_t)b * KENC + 768 + k] = 0;
    }
    if (idx < B_SZ * H_SZ) c[idx] = 0.f;
    if (idx < B_SZ * I_SZ) {
        const int b = idx >> 8, i = idx & 255;
        const float v = x0[(size_t)b * (T_SZ * I_SZ) + i];
        const ushort hi = f2bf(v), lo = f2bf(v - bf2f(hi));
        ushort* xd = Aenc0 + (size_t)b * KENC;
        xd[i] = hi;
        xd[256 + i] = hi;
        xd[512 + i] = lo;
    }
    if (idx < B_SZ * 64) {
        const int b = idx >> 6, col = idx & 63;
        ushort v0 = 0;
        if (col < 8)       v0 = f2bf(embed_W[col]);
        else if (col < 16) v0 = f2bf(embed_W[col - 8]);
        else if (col < 24) { const float v = embed_W[col - 16]; const ushort hi = f2bf(v); v0 = f2bf(v - bf2f(hi)); }
        Adec0[(size_t)b * KDEC + col] = v0;
        if (col >= 24) Adec1[(size_t)b * KDEC + col] = 0;
    }
}

extern "C" void kernel_launch(void* const* d_in, const int* in_sizes, int n_in,
                              void* d_out, int out_size, void* d_ws, size_t ws_size,
                              hipStream_t stream)
{
    const float* x_hist  = (const float*)d_in[0];
    const float* enc_Wih = (const float*)d_in[1];
    const float* enc_Whh = (const float*)d_in[2];
    const float* enc_b   = (const float*)d_in[3];
    const float* embed_W = (const float*)d_in[4];
    const float* dec_Wih = (const float*)d_in[5];
    const float* dec_Whh = (const float*)d_in[6];
    const float* dec_b   = (const float*)d_in[7];
    const float* fc_W    = (const float*)d_in[8];
    const float* fc_b    = (const float*)d_in[9];
    float* out = (float*)d_out;

    char* p = (char*)d_ws;
    auto alloc = [&](size_t bytes) {
        char* r = p;
        p += (bytes + 255) & ~(size_t)255;
        return r;
    };
    ushort* W_enc  = (ushort*)alloc((size_t)4096 * KENC * 2);   // 30 MB
    ushort* W_dec  = (ushort*)alloc((size_t)4096 * KDEC * 2);   // 24.5 MB
    ushort* W_fc   = (ushort*)alloc((size_t)1024 * KFC * 2);    // 6 MB
    ushort* A_enc0 = (ushort*)alloc((size_t)B_SZ * KENC * 2);   // 3.75 MB
    ushort* A_enc1 = (ushort*)alloc((size_t)B_SZ * KENC * 2);
    ushort* A_dec0 = (ushort*)alloc((size_t)B_SZ * KDEC * 2);   // 3.06 MB
    ushort* A_dec1 = (ushort*)alloc((size_t)B_SZ * KDEC * 2);
    float*  cbuf   = (float*)alloc((size_t)B_SZ * H_SZ * 4);    // 2 MB
    float*  bpe    = (float*)alloc(4096 * 4);
    float*  bpd    = (float*)alloc(4096 * 4);

    const dim3 blk(256);
    hipLaunchKernelGGL(pack_enc, dim3(15, 4096), blk, 0, stream, enc_Wih, enc_Whh, enc_b, W_enc, bpe);
    hipLaunchKernelGGL(pack_dec, dim3(13, 4096), blk, 0, stream, dec_Wih, dec_Whh, dec_b, W_dec, bpd);
    hipLaunchKernelGGL(pack_fc,  dim3(12, 1024), blk, 0, stream, fc_W, W_fc);
    hipLaunchKernelGGL(init_all, dim3(6144), blk, 0, stream, x_hist, embed_W, cbuf, A_enc0, A_dec0, A_dec1);

    ushort* Ae[2] = {A_enc0, A_enc1};
    ushort* Ad[2] = {A_dec0, A_dec1};

    // ---- Encoder ----
    for (int t = 0; t < T_SZ; ++t) {
        ushort* hdst; int ldh; const float* xs; ushort* xd;
        if (t < T_SZ - 1) {
            hdst = Ae[(t + 1) & 1] + 768; ldh = KENC;
            xs = x_hist + (size_t)(t + 1) * I_SZ;
            xd = Ae[(t + 1) & 1];
        } else {
            hdst = Ad[0] + 64; ldh = KDEC;
            xs = nullptr; xd = nullptr;
        }
        hipLaunchKernelGGL(lstm_step, dim3(256), blk, 0, stream,
                           Ae[t & 1], KENC, W_enc, bpe, cbuf, hdst, ldh, xs, xd);
    }

    // ---- Decoder ----
    for (int t = 0; t < FUT; ++t) {
        hipLaunchKernelGGL(lstm_step, dim3(256), blk, 0, stream,
                           Ad[t & 1], KDEC, W_dec, bpd, cbuf,
                           Ad[(t + 1) & 1] + 64, KDEC,
                           (const float*)nullptr, (ushort*)nullptr);
        float* logits = out + (size_t)t * V_SZ;   // [B, FUT, V]
        hipLaunchKernelGGL(fc_gemm, dim3(256), blk, 0, stream,
                           Ad[(t + 1) & 1] + 64, KDEC, W_fc, fc_b, logits, FUT * V_SZ);
        hipLaunchKernelGGL(argmax_embed, dim3(512), blk, 0, stream,
                           logits, FUT * V_SZ, embed_W, Ad[(t + 1) & 1]);
    }
}

// Round 3
// 18034.555 us; speedup vs baseline: 2.7914x; 1.2383x over previous
//
#include <hip/hip_runtime.h>
#include <cmath>

typedef __attribute__((ext_vector_type(8))) short short8;
typedef __attribute__((ext_vector_type(4))) float f32x4;

#define B_SZ 512
#define T_SZ 256
#define I_SZ 256
#define H_SZ 1024
#define V_SZ 1024
#define E_SZ 8
#define FUT 64

// Split-bf16 concatenated K layouts:
//   enc A: [x_hi(256) | x_hi(256) | x_lo(256) | h_hi(1024) | h_hi(1024) | h_lo(1024)]
//   dec A: [xc(64: x_hi8|x_hi8|x_lo8|0*40)   | h_hi(1024) | h_hi(1024) | h_lo(1024)]
//   fc  A: hcat = [h_hi | h_hi | h_lo]  (lives inside dec A at col 64)
#define KENC 3840
#define KDEC 3136
#define KFC  3072

static __device__ __forceinline__ ushort f2bf(float v) {
    uint32_t u = __float_as_uint(v);
    uint32_t r = (u + 0x7fffu + ((u >> 16) & 1u)) >> 16;
    return (ushort)r;
}
static __device__ __forceinline__ float bf2f(ushort b) {
    return __uint_as_float(((uint32_t)b) << 16);
}

#define GLD16(gp, lp)                                                          \
    __builtin_amdgcn_global_load_lds(                                         \
        (const __attribute__((address_space(1))) void*)(gp),                  \
        (__attribute__((address_space(3))) void*)(lp), 16, 0, 0)

// LDS tiles are [rows][64 bf16] = [rows][128 B] = 8 16B-slots per row.
// XOR swizzle (T2): LDS write stays linear (global_load_lds requirement);
// the GLOBAL source column is pre-swizzled slot_g = slot_l ^ (row&7), and the
// ds_read column applies the same XOR: slot_phys = slot_log ^ (row&7).
// For all fragment rows here, row&7 == lane&7.

// ---------------------------------------------------------------------------
// Fused LSTM step: Z[512,4096] = A[512,K] @ W[4096,K]^T (bf16 MFMA, fp32 acc)
// with gate-permuted columns (n' = jhi*64 + g*16 + jlo), then gates + c update
// + h split written as bf16 hi/lo into the NEXT step's A buffer. Optionally
// converts x_{t+1} into the next A buffer too.
// Tile 64(M) x 128(N'), BK=64, 4 waves (2x2), wave tile 32x64. Grid: 256 flat.
// ---------------------------------------------------------------------------
__global__ __launch_bounds__(256) void lstm_step(
    const ushort* __restrict__ A, int K,
    const ushort* __restrict__ W,
    const float* __restrict__ bias,          // [4096] gate-permuted
    float* __restrict__ c,                   // [512,1024] fp32, in-place
    ushort* __restrict__ hdest, int ldh,     // hcat base: writes j, 1024+j, 2048+j
    const float* __restrict__ xsrc,          // x_hist + (t+1)*I (row stride T*I) or null
    ushort* __restrict__ xdest)              // next A_enc base or null
{
    __shared__ __align__(16) ushort As[2][64 * 64];
    __shared__ __align__(16) ushort Ws[2][128 * 64];

    const int tid = threadIdx.x;
    const int lane = tid & 63;
    const int wid = tid >> 6;
    const int wm = wid >> 1;            // 0..1
    const int wn = wid & 1;             // 0..1

    // XCD swizzle: xcd = flat&7 owns a contiguous 512-col slice of W (L2-fit).
    const int flat = blockIdx.x;        // 0..255
    const int slot = flat >> 3;
    const int n_blk = (flat & 7) * 4 + (slot & 3);   // 0..31
    const int m_blk = slot >> 2;                     // 0..7
    const int m0 = m_blk * 64;
    const int n0 = n_blk * 128;

    const int lrow = lane >> 3;                       // 0..7 (= LDS row & 7)
    const int lcol = (((lane & 7) ^ lrow) * 8);       // pre-swizzled global col

    f32x4 acc[2][4];
#pragma unroll
    for (int i = 0; i < 2; ++i)
#pragma unroll
        for (int j = 0; j < 4; ++j) { f32x4 z = {0.f, 0.f, 0.f, 0.f}; acc[i][j] = z; }

    const int nk = K / 64;

    // prologue: stage chunk 0 into buf 0
#pragma unroll
    for (int r = 0; r < 2; ++r)
        GLD16(A + (size_t)(m0 + r * 32 + wid * 8 + lrow) * K + lcol,
              &As[0][(r * 32 + wid * 8) * 64]);
#pragma unroll
    for (int r = 0; r < 4; ++r)
        GLD16(W + (size_t)(n0 + r * 32 + wid * 8 + lrow) * K + lcol,
              &Ws[0][(r * 32 + wid * 8) * 64]);

    int buf = 0;
    for (int kt = 0; kt < nk; ++kt) {
        __syncthreads();                 // drains vmcnt: chunk `buf` is ready
        if (kt + 1 < nk) {
            const int k0 = (kt + 1) * 64;
#pragma unroll
            for (int r = 0; r < 2; ++r)
                GLD16(A + (size_t)(m0 + r * 32 + wid * 8 + lrow) * K + k0 + lcol,
                      &As[buf ^ 1][(r * 32 + wid * 8) * 64]);
#pragma unroll
            for (int r = 0; r < 4; ++r)
                GLD16(W + (size_t)(n0 + r * 32 + wid * 8 + lrow) * K + k0 + lcol,
                      &Ws[buf ^ 1][(r * 32 + wid * 8) * 64]);
        }
#pragma unroll
        for (int kk = 0; kk < 2; ++kk) {
            short8 af[2], wf[4];
#pragma unroll
            for (int m = 0; m < 2; ++m)
                af[m] = *(const short8*)&As[buf][(wm * 32 + m * 16 + (lane & 15)) * 64 +
                                                 (((kk * 4 + (lane >> 4)) ^ (lane & 7)) * 8)];
#pragma unroll
            for (int n = 0; n < 4; ++n)
                wf[n] = *(const short8*)&Ws[buf][(wn * 64 + n * 16 + (lane & 15)) * 64 +
                                                 (((kk * 4 + (lane >> 4)) ^ (lane & 7)) * 8)];
#pragma unroll
            for (int m = 0; m < 2; ++m)
#pragma unroll
                for (int n = 0; n < 4; ++n)
                    acc[m][n] = __builtin_amdgcn_mfma_f32_16x16x32_bf16(
                        af[m], wf[n], acc[m][n], 0, 0, 0);
        }
        buf ^= 1;
    }

    // ---- fused gate epilogue ----
    const int jlo = lane & 15;
    const int rg = lane >> 4;
    const int nb = n0 + wn * 64;                 // 64-aligned
    const int j = (nb >> 6) * 16 + jlo;          // h column
    const float bi_ = bias[nb + jlo];
    const float bf_ = bias[nb + 16 + jlo];
    const float bg_ = bias[nb + 32 + jlo];
    const float bo_ = bias[nb + 48 + jlo];
#pragma unroll
    for (int m = 0; m < 2; ++m) {
        const int row0 = m0 + wm * 32 + m * 16 + rg * 4;
#pragma unroll
        for (int r = 0; r < 4; ++r) {
            const int row = row0 + r;
            const float zi = acc[m][0][r] + bi_;
            const float zf = acc[m][1][r] + bf_;
            const float zg = acc[m][2][r] + bg_;
            const float zo = acc[m][3][r] + bo_;
            const float ig = 1.f / (1.f + expf(-zi));
            const float fg = 1.f / (1.f + expf(-zf));
            const float gg = tanhf(zg);
            const float og = 1.f / (1.f + expf(-zo));
            const size_t ci = (size_t)row * H_SZ + j;
            const float cn = fg * c[ci] + ig * gg;
            c[ci] = cn;
            const float hv = og * tanhf(cn);
            const ushort hh = f2bf(hv);
            const ushort hl = f2bf(hv - bf2f(hh));
            ushort* hd = hdest + (size_t)row * ldh;
            hd[j] = hh;
            hd[H_SZ + j] = hh;
            hd[2 * H_SZ + j] = hl;
        }
    }

    // ---- fused x_{t+1} hi/lo conversion into next A buffer ----
    if (xdest) {
        const int ft = (blockIdx.x * 256 + tid) * 2;   // 131072 elems total
#pragma unroll
        for (int e = 0; e < 2; ++e) {
            const int idx = ft + e;
            const int b = idx >> 8, i = idx & 255;
            const float v = xsrc[(size_t)b * (T_SZ * I_SZ) + i];
            const ushort hi = f2bf(v), lo = f2bf(v - bf2f(hi));
            ushort* xd = xdest + (size_t)b * KENC;
            xd[i] = hi;
            xd[256 + i] = hi;
            xd[512 + i] = lo;
        }
    }
}

// ---------------------------------------------------------------------------
// fc GEMM: logits[512,1024] = hcat[512,3072] @ W_fc[1024,3072]^T + fc_b.
// Tile 32x64, 4 waves (2x2), wave tile 16x32. Grid: 256 flat (XCD-swizzled).
// ---------------------------------------------------------------------------
__global__ __launch_bounds__(256) void fc_gemm(
    const ushort* __restrict__ A, int lda,
    const ushort* __restrict__ W,
    const float* __restrict__ bias,
    float* __restrict__ out, int ldo)
{
    __shared__ __align__(16) ushort As[2][32 * 64];
    __shared__ __align__(16) ushort Ws[2][64 * 64];
    const int tid = threadIdx.x, lane = tid & 63, wid = tid >> 6;
    const int wm = wid >> 1, wn = wid & 1;
    const int flat = blockIdx.x;
    const int slot = flat >> 3;
    const int n_blk = (flat & 7) * 2 + (slot & 1);   // 0..15
    const int m_blk = slot >> 1;                     // 0..15
    const int m0 = m_blk * 32, n0 = n_blk * 64;
    const int lrow = lane >> 3;
    const int lcol = (((lane & 7) ^ lrow) * 8);      // pre-swizzled global col

    f32x4 acc[2];
    { f32x4 z = {0.f, 0.f, 0.f, 0.f}; acc[0] = z; acc[1] = z; }
    const int nk = KFC / 64;   // 48

    GLD16(A + (size_t)(m0 + wid * 8 + lrow) * lda + lcol, &As[0][(wid * 8) * 64]);
#pragma unroll
    for (int r = 0; r < 2; ++r)
        GLD16(W + (size_t)(n0 + r * 32 + wid * 8 + lrow) * KFC + lcol,
              &Ws[0][(r * 32 + wid * 8) * 64]);

    int buf = 0;
    for (int kt = 0; kt < nk; ++kt) {
        __syncthreads();
        if (kt + 1 < nk) {
            const int k0 = (kt + 1) * 64;
            GLD16(A + (size_t)(m0 + wid * 8 + lrow) * lda + k0 + lcol,
                  &As[buf ^ 1][(wid * 8) * 64]);
#pragma unroll
            for (int r = 0; r < 2; ++r)
                GLD16(W + (size_t)(n0 + r * 32 + wid * 8 + lrow) * KFC + k0 + lcol,
                      &Ws[buf ^ 1][(r * 32 + wid * 8) * 64]);
        }
#pragma unroll
        for (int kk = 0; kk < 2; ++kk) {
            const short8 af = *(const short8*)&As[buf][(wm * 16 + (lane & 15)) * 64 +
                                                       (((kk * 4 + (lane >> 4)) ^ (lane & 7)) * 8)];
            short8 wf[2];
#pragma unroll
            for (int n = 0; n < 2; ++n)
                wf[n] = *(const short8*)&Ws[buf][(wn * 32 + n * 16 + (lane & 15)) * 64 +
                                                 (((kk * 4 + (lane >> 4)) ^ (lane & 7)) * 8)];
#pragma unroll
            for (int n = 0; n < 2; ++n)
                acc[n] = __builtin_amdgcn_mfma_f32_16x16x32_bf16(af, wf[n], acc[n], 0, 0, 0);
        }
        buf ^= 1;
    }

    const int jl = lane & 15, rg = lane >> 4;
#pragma unroll
    for (int n = 0; n < 2; ++n) {
        const int col = n0 + wn * 32 + n * 16 + jl;
        const float bv = bias[col];
#pragma unroll
        for (int r = 0; r < 4; ++r) {
            const int row = m0 + wm * 16 + rg * 4 + r;
            out[(size_t)row * ldo + col] = acc[n][r] + bv;
        }
    }
}

// ---------------------------------------------------------------------------
// Row argmax (first-occurrence) fused with embedding gather + hi/lo split
// into the next decoder A buffer's xcomb columns.
// ---------------------------------------------------------------------------
__global__ __launch_bounds__(256) void argmax_embed(
    const float* __restrict__ logits, int ldl,
    const float* __restrict__ embed_W,
    ushort* __restrict__ xdest)
{
    const int b = blockIdx.x;
    const float* row = logits + (size_t)b * ldl;
    const int tid = threadIdx.x;
    float best = -INFINITY;
    int bi = V_SZ;
#pragma unroll
    for (int v = tid; v < V_SZ; v += 256) {
        const float x = row[v];
        if (x > best) { best = x; bi = v; }
    }
    __shared__ float sv[256];
    __shared__ int si[256];
    sv[tid] = best; si[tid] = bi;
    __syncthreads();
    for (int s = 128; s > 0; s >>= 1) {
        if (tid < s) {
            const float ov = sv[tid + s]; const int oi = si[tid + s];
            if (ov > sv[tid] || (ov == sv[tid] && oi < si[tid])) { sv[tid] = ov; si[tid] = oi; }
        }
        __syncthreads();
    }
    if (tid < E_SZ) {
        const int yb = si[0];
        const float v = embed_W[(size_t)yb * E_SZ + tid];
        const ushort hi = f2bf(v), lo = f2bf(v - bf2f(hi));
        ushort* xd = xdest + (size_t)b * KDEC;
        xd[tid] = hi;
        xd[8 + tid] = hi;
        xd[16 + tid] = lo;
    }
}

// ---------------------------------------------------------------------------
// Weight packing (gate-permuted rows, split-bf16 concatenated K).
// ---------------------------------------------------------------------------
__global__ void pack_enc(const float* __restrict__ Wih, const float* __restrict__ Whh,
                         const float* __restrict__ b, ushort* __restrict__ Wp,
                         float* __restrict__ bp)
{
    const int k = blockIdx.x * 256 + threadIdx.x;   // < 3840
    const int np = blockIdx.y;                      // < 4096
    const int orig = ((np >> 4) & 3) * H_SZ + (np >> 6) * 16 + (np & 15);
    float v; bool lo = false;
    if (k < 256)        v = Wih[(size_t)orig * I_SZ + k];
    else if (k < 512) { v = Wih[(size_t)orig * I_SZ + k - 256]; lo = true; }
    else if (k < 768)   v = Wih[(size_t)orig * I_SZ + k - 512];
    else if (k < 1792)  v = Whh[(size_t)orig * H_SZ + k - 768];
    else if (k < 2816) { v = Whh[(size_t)orig * H_SZ + k - 1792]; lo = true; }
    else                v = Whh[(size_t)orig * H_SZ + k - 2816];
    const ushort hi = f2bf(v);
    Wp[(size_t)np * KENC + k] = lo ? f2bf(v - bf2f(hi)) : hi;
    if (k == 0) bp[np] = b[orig];
}

__global__ void pack_dec(const float* __restrict__ Wih, const float* __restrict__ Whh,
                         const float* __restrict__ b, ushort* __restrict__ Wp,
                         float* __restrict__ bp)
{
    const int k = blockIdx.x * 256 + threadIdx.x;
    const int np = blockIdx.y;
    if (k >= KDEC) return;
    const int orig = ((np >> 4) & 3) * H_SZ + (np >> 6) * 16 + (np & 15);
    float v = 0.f; bool lo = false;
    if (k < 8)          v = Wih[(size_t)orig * E_SZ + k];
    else if (k < 16)  { v = Wih[(size_t)orig * E_SZ + k - 8]; lo = true; }
    else if (k < 24)    v = Wih[(size_t)orig * E_SZ + k - 16];
    else if (k < 64)    v = 0.f;
    else if (k < 1088)  v = Whh[(size_t)orig * H_SZ + k - 64];
    else if (k < 2112) { v = Whh[(size_t)orig * H_SZ + k - 1088]; lo = true; }
    else                v = Whh[(size_t)orig * H_SZ + k - 2112];
    const ushort hi = f2bf(v);
    Wp[(size_t)np * KDEC + k] = lo ? f2bf(v - bf2f(hi)) : hi;
    if (k == 0) bp[np] = b[orig];
}

__global__ void pack_fc(const float* __restrict__ W, ushort* __restrict__ Wp)
{
    const int k = blockIdx.x * 256 + threadIdx.x;   // < 3072
    const int np = blockIdx.y;                      // < 1024
    float v; bool lo = false;
    if (k < 1024)       v = W[(size_t)np * H_SZ + k];
    else if (k < 2048) { v = W[(size_t)np * H_SZ + k - 1024]; lo = true; }
    else                v = W[(size_t)np * H_SZ + k - 2048];
    const ushort hi = f2bf(v);
    Wp[(size_t)np * KFC + k] = lo ? f2bf(v - bf2f(hi)) : hi;
}

// ---------------------------------------------------------------------------
// Init: zero c, zero h-region of A_enc[0], convert x(0), write xcomb(0) from
// embed row 0, zero the pad columns of both decoder A buffers.
// ---------------------------------------------------------------------------
__global__ void init_all(const float* __restrict__ x0,
                         const float* __restrict__ embed_W,
                         float* __restrict__ c,
                         ushort* __restrict__ Aenc0,
                         ushort* __restrict__ Adec0,
                         ushort* __restrict__ Adec1)
{
    const int idx = blockIdx.x * 256 + threadIdx.x;   // < 512*3072
    {
        const int b = idx / 3072, k = idx % 3072;
        Aenc0[(size_t)b * KENC + 768 + k] = 0;
    }
    if (idx < B_SZ * H_SZ) c[idx] = 0.f;
    if (idx < B_SZ * I_SZ) {
        const int b = idx >> 8, i = idx & 255;
        const float v = x0[(size_t)b * (T_SZ * I_SZ) + i];
        const ushort hi = f2bf(v), lo = f2bf(v - bf2f(hi));
        ushort* xd = Aenc0 + (size_t)b * KENC;
        xd[i] = hi;
        xd[256 + i] = hi;
        xd[512 + i] = lo;
    }
    if (idx < B_SZ * 64) {
        const int b = idx >> 6, col = idx & 63;
        ushort v0 = 0;
        if (col < 8)       v0 = f2bf(embed_W[col]);
        else if (col < 16) v0 = f2bf(embed_W[col - 8]);
        else if (col < 24) { const float v = embed_W[col - 16]; const ushort hi = f2bf(v); v0 = f2bf(v - bf2f(hi)); }
        Adec0[(size_t)b * KDEC + col] = v0;
        if (col >= 24) Adec1[(size_t)b * KDEC + col] = 0;
    }
}

extern "C" void kernel_launch(void* const* d_in, const int* in_sizes, int n_in,
                              void* d_out, int out_size, void* d_ws, size_t ws_size,
                              hipStream_t stream)
{
    const float* x_hist  = (const float*)d_in[0];
    const float* enc_Wih = (const float*)d_in[1];
    const float* enc_Whh = (const float*)d_in[2];
    const float* enc_b   = (const float*)d_in[3];
    const float* embed_W = (const float*)d_in[4];
    const float* dec_Wih = (const float*)d_in[5];
    const float* dec_Whh = (const float*)d_in[6];
    const float* dec_b   = (const float*)d_in[7];
    const float* fc_W    = (const float*)d_in[8];
    const float* fc_b    = (const float*)d_in[9];
    float* out = (float*)d_out;

    char* p = (char*)d_ws;
    auto alloc = [&](size_t bytes) {
        char* r = p;
        p += (bytes + 255) & ~(size_t)255;
        return r;
    };
    ushort* W_enc  = (ushort*)alloc((size_t)4096 * KENC * 2);   // 30 MB
    ushort* W_dec  = (ushort*)alloc((size_t)4096 * KDEC * 2);   // 24.5 MB
    ushort* W_fc   = (ushort*)alloc((size_t)1024 * KFC * 2);    // 6 MB
    ushort* A_enc0 = (ushort*)alloc((size_t)B_SZ * KENC * 2);   // 3.75 MB
    ushort* A_enc1 = (ushort*)alloc((size_t)B_SZ * KENC * 2);
    ushort* A_dec0 = (ushort*)alloc((size_t)B_SZ * KDEC * 2);   // 3.06 MB
    ushort* A_dec1 = (ushort*)alloc((size_t)B_SZ * KDEC * 2);
    float*  cbuf   = (float*)alloc((size_t)B_SZ * H_SZ * 4);    // 2 MB
    float*  bpe    = (float*)alloc(4096 * 4);
    float*  bpd    = (float*)alloc(4096 * 4);

    const dim3 blk(256);
    hipLaunchKernelGGL(pack_enc, dim3(15, 4096), blk, 0, stream, enc_Wih, enc_Whh, enc_b, W_enc, bpe);
    hipLaunchKernelGGL(pack_dec, dim3(13, 4096), blk, 0, stream, dec_Wih, dec_Whh, dec_b, W_dec, bpd);
    hipLaunchKernelGGL(pack_fc,  dim3(12, 1024), blk, 0, stream, fc_W, W_fc);
    hipLaunchKernelGGL(init_all, dim3(6144), blk, 0, stream, x_hist, embed_W, cbuf, A_enc0, A_dec0, A_dec1);

    ushort* Ae[2] = {A_enc0, A_enc1};
    ushort* Ad[2] = {A_dec0, A_dec1};

    // ---- Encoder ----
    for (int t = 0; t < T_SZ; ++t) {
        ushort* hdst; int ldh; const float* xs; ushort* xd;
        if (t < T_SZ - 1) {
            hdst = Ae[(t + 1) & 1] + 768; ldh = KENC;
            xs = x_hist + (size_t)(t + 1) * I_SZ;
            xd = Ae[(t + 1) & 1];
        } else {
            hdst = Ad[0] + 64; ldh = KDEC;
            xs = nullptr; xd = nullptr;
        }
        hipLaunchKernelGGL(lstm_step, dim3(256), blk, 0, stream,
                           Ae[t & 1], KENC, W_enc, bpe, cbuf, hdst, ldh, xs, xd);
    }

    // ---- Decoder ----
    for (int t = 0; t < FUT; ++t) {
        hipLaunchKernelGGL(lstm_step, dim3(256), blk, 0, stream,
                           Ad[t & 1], KDEC, W_dec, bpd, cbuf,
                           Ad[(t + 1) & 1] + 64, KDEC,
                           (const float*)nullptr, (ushort*)nullptr);
        float* logits = out + (size_t)t * V_SZ;   // [B, FUT, V]
        hipLaunchKernelGGL(fc_gemm, dim3(256), blk, 0, stream,
                           Ad[(t + 1) & 1] + 64, KDEC, W_fc, fc_b, logits, FUT * V_SZ);
        hipLaunchKernelGGL(argmax_embed, dim3(512), blk, 0, stream,
                           logits, FUT * V_SZ, embed_W, Ad[(t + 1) & 1]);
    }
}